// Round 1
// 671.528 us; speedup vs baseline: 1.5861x; 1.5861x over previous
//
#include <hip/hip_runtime.h>
#include <hip/hip_bf16.h>
#include <math.h>

#define LLEN 30
#define DMOD 14
#define NH 8
#define NFF 50
#define LN_EPS 1e-5f
#define K1P 448           // padded inner dim for f (420 -> 448 = 14*32)
#define NREC_W1 14336     // 14 chunks * 4 slots * 256 rows
#define NREC_WR 3584      // 14 chunks * 4 slots * 64 rows
#define NREC_W2 2048      // 8 chunks * 4 slots * 64 rows

typedef unsigned short u16;
typedef unsigned int u32;
typedef __attribute__((ext_vector_type(8))) short s16x8;   // 8 bf16 = 4 VGPRs (MFMA A/B frag)
typedef __attribute__((ext_vector_type(4))) float f32x4;   // MFMA C/D frag

__device__ __forceinline__ float bflo(u32 v) {
  union { u32 u; float f; } w; w.u = v << 16; return w.f;
}
__device__ __forceinline__ u16 f2bf(float f) {
  union { float f; u32 u; } w; w.f = f;
  u32 x = w.u;
  x = (x + 0x7FFFu + ((x >> 16) & 1u)) >> 16;
  return (u16)x;
}
__device__ __forceinline__ u32 pk2(float lo, float hi) {
  return (u32)f2bf(lo) | ((u32)f2bf(hi) << 16);
}

// Exact replicate-pad 25-tap MA removal on one contiguous 30-float LDS row.
__device__ __forceinline__ void decomp_row_lds(float* row) {
  float xv[30];
  const float2* r2 = (const float2*)row;
  #pragma unroll
  for (int j = 0; j < 15; ++j) { float2 w = r2[j]; xv[2*j] = w.x; xv[2*j+1] = w.y; }
  float2* w2 = (float2*)row;
  float ws = 13.f * xv[0];
  #pragma unroll
  for (int j = 1; j <= 12; ++j) ws += xv[j];
  float rprev = xv[0] - ws * (1.f / 25.f);
  #pragma unroll
  for (int jj = 1; jj < 30; ++jj) {
    const int hi = (jj + 12 > 29) ? 29 : jj + 12;
    const int lo = (jj - 13 < 0) ? 0 : jj - 13;
    ws += xv[hi] - xv[lo];
    const float r = xv[jj] - ws * (1.f / 25.f);
    if (jj & 1) { w2[jj >> 1] = make_float2(rprev, r); } else { rprev = r; }
  }
}

// ============================ Front-end kernel ==============================
// Unchanged from prior round except: f_out row stride 420 -> 448 (bf16) with
// zero pad in cols 420..447 so the MFMA head can use aligned 16B fragments.
__global__ __launch_bounds__(64, 6) void fe_kernel(
    const float* __restrict__ x,
    const float* __restrict__ W_emb, const float* __restrict__ b_emb,
    const float* __restrict__ Wq, const float* __restrict__ bq,
    const float* __restrict__ Wk, const float* __restrict__ bk,
    const float* __restrict__ Wv, const float* __restrict__ bv,
    const float* __restrict__ Wo, const float* __restrict__ bo,
    const float* __restrict__ W_ff1, const float* __restrict__ W_ff2,
    const float* __restrict__ g_norm, const float* __restrict__ b_norm,
    const float* __restrict__ W_dy, const float* __restrict__ b_dy,
    const float* __restrict__ channels,
    u16* __restrict__ f_out, int Btot)
{
  const int t    = threadIdx.x;
  const int half = t >> 5;
  const int l    = t & 31;
  const int base = half << 5;
  const bool act = (l < LLEN);
  const int b    = blockIdx.x * 2 + half;
  const bool live = act && (b < Btot);

  __shared__ float pool[2][600];
  __shared__ float adjLDS[DMOD][16];
  __shared__ float MV[2][32];
  __shared__ float TW[2][4];
  __shared__ int   TD[2][4];

  // ---- P0: load x; lanes t<14 compute adj; zero-pad f row tail ----
  float xr[DMOD];
  if (live) {
    const float2* xp2 = (const float2*)(x + (size_t)b * 420 + l * DMOD);
    #pragma unroll
    for (int j = 0; j < 7; ++j) { float2 v = xp2[j]; xr[2*j] = v.x; xr[2*j+1] = v.y; }
  } else {
    #pragma unroll
    for (int d = 0; d < DMOD; ++d) xr[d] = 0.f;
  }
  if (l < 28 && b < Btot) f_out[(size_t)b * K1P + 420 + l] = (u16)0;
  if (t < DMOD) {
    float row[DMOD]; float m = -1e30f;
    #pragma unroll
    for (int j = 0; j < DMOD; ++j) { row[j] = channels[t * DMOD + j]; m = fmaxf(m, row[j]); }
    float s = 0.f;
    #pragma unroll
    for (int j = 0; j < DMOD; ++j) { row[j] = __expf(row[j] - m); s += row[j]; }
    const float inv = 1.f / s;
    #pragma unroll
    for (int j = 0; j < DMOD; ++j) adjLDS[t][j] = row[j] * inv;
  }

  // ---- P1: conv1d embed ----
  float xe[DMOD];
  #pragma unroll
  for (int o = 0; o < DMOD; ++o) xe[o] = b_emb[o];
  #pragma unroll
  for (int c = 0; c < DMOD; ++c) {
    float xm = __shfl(xr[c], t - 1);
    float xp = __shfl(xr[c], t + 1);
    xm = (l == 0) ? 0.f : xm;
    xp = (l >= LLEN - 1) ? 0.f : xp;
    const float xc = xr[c];
    #pragma unroll
    for (int o = 0; o < DMOD; ++o) {
      const float* wp = W_emb + o * (DMOD * 3) + c * 3;
      xe[o] += wp[0] * xm + wp[1] * xc + wp[2] * xp;
    }
  }

  // ---- P2: q,k,v ----
  float q[NH], k[NH], v[NH];
  #pragma unroll
  for (int h = 0; h < NH; ++h) { q[h] = bq[h]; k[h] = bk[h]; v[h] = bv[h]; }
  #pragma unroll
  for (int d = 0; d < DMOD; ++d) {
    const float e = xe[d];
    #pragma unroll
    for (int h = 0; h < NH; ++h) {
      q[h] += Wq[d * NH + h] * e;
      k[h] += Wk[d * NH + h] * e;
      v[h] += Wv[d * NH + h] * e;
    }
  }

  // ---- P3: autocorr ----
  if (act) {
    float2* qr = (float2*)&pool[half][l * 10];
    qr[0] = make_float2(q[0], q[1]); qr[1] = make_float2(q[2], q[3]);
    qr[2] = make_float2(q[4], q[5]); qr[3] = make_float2(q[6], q[7]);
    float2* kr = (float2*)&pool[half][300 + l * 10];
    kr[0] = make_float2(k[0], k[1]); kr[1] = make_float2(k[2], k[3]);
    kr[2] = make_float2(k[4], k[5]); kr[3] = make_float2(k[6], k[7]);
  }
  __syncthreads();
  if (act) {
    float acc = 0.f;
    #pragma unroll 5
    for (int s = 0; s < LLEN; ++s) {
      int rq = l + s; if (rq >= LLEN) rq -= LLEN;
      const float2* qa = (const float2*)&pool[half][rq * 10];
      const float2* ka = (const float2*)&pool[half][300 + s * 10];
      float2 a0 = qa[0], a1 = qa[1], a2 = qa[2], a3 = qa[3];
      float2 b0 = ka[0], b1 = ka[1], b2 = ka[2], b3 = ka[3];
      acc += a0.x * b0.x + a0.y * b0.y + a1.x * b1.x + a1.y * b1.y
           + a2.x * b2.x + a2.y * b2.y + a3.x * b3.x + a3.y * b3.y;
    }
    MV[half][l] = acc * (1.f / NH);
  }
  __syncthreads();

  // ---- P4: top-3 + softmax ----
  if (l == 0) {
    float v1 = -1e30f, v2 = -1e30f, v3 = -1e30f; int i1 = 0, i2 = 0, i3 = 0;
    for (int i = 0; i < LLEN; ++i) {
      const float vv = MV[half][i];
      if (vv > v1)      { v3 = v2; i3 = i2; v2 = v1; i2 = i1; v1 = vv; i1 = i; }
      else if (vv > v2) { v3 = v2; i3 = i2; v2 = vv; i2 = i; }
      else if (vv > v3) { v3 = vv; i3 = i; }
    }
    const float e2 = __expf(v2 - v1), e3 = __expf(v3 - v1);
    const float inv = 1.f / (1.f + e2 + e3);
    TW[half][0] = inv; TW[half][1] = e2 * inv; TW[half][2] = e3 * inv;
    TD[half][0] = i1; TD[half][1] = i2; TD[half][2] = i3;
  }
  __syncthreads();

  // ---- P5: weighted circular gather ----
  float agg[NH];
  #pragma unroll
  for (int h = 0; h < NH; ++h) agg[h] = 0.f;
  #pragma unroll
  for (int kk = 0; kk < 3; ++kk) {
    const float w = TW[half][kk];
    const int dd = TD[half][kk];
    int sidx = l + dd; if (sidx >= LLEN) sidx -= LLEN;
    const int src = base + sidx;
    #pragma unroll
    for (int h = 0; h < NH; ++h) agg[h] += w * __shfl(v[h], src);
  }

  // ---- P6: out-proj + residual ----
  #pragma unroll
  for (int d = 0; d < DMOD; ++d) {
    float a = bo[d];
    #pragma unroll
    for (int h = 0; h < NH; ++h) a += agg[h] * Wo[h * DMOD + d];
    xe[d] += a;
  }
  __syncthreads();

  // ---- P7: decomp #1 ----
  if (act) {
    #pragma unroll
    for (int d = 0; d < DMOD; ++d) pool[half][d * LLEN + l] = xe[d];
  }
  __syncthreads();
  if (l < DMOD) decomp_row_lds(&pool[half][l * LLEN]);
  __syncthreads();
  float s1[DMOD];
  if (act) {
    #pragma unroll
    for (int d = 0; d < DMOD; ++d) s1[d] = pool[half][d * LLEN + l];
  } else {
    #pragma unroll
    for (int d = 0; d < DMOD; ++d) s1[d] = 0.f;
  }
  __syncthreads();

  // ---- P8: FFN ----
  float y[DMOD];
  #pragma unroll
  for (int d = 0; d < DMOD; ++d) y[d] = 0.f;
  for (int f = 0; f < NFF; ++f) {
    float a = 0.f;
    #pragma unroll
    for (int d = 0; d < DMOD; ++d) a += s1[d] * W_ff1[d * NFF + f];
    const float g = 0.5f * a * (1.f + erff(a * 0.70710678118654752f));
    #pragma unroll
    for (int d = 0; d < DMOD; ++d) y[d] += g * W_ff2[f * DMOD + d];
  }

  // ---- P9: decomp #2 ----
  if (act) {
    #pragma unroll
    for (int d = 0; d < DMOD; ++d) pool[half][d * LLEN + l] = s1[d] + y[d];
  }
  __syncthreads();
  if (l < DMOD) decomp_row_lds(&pool[half][l * LLEN]);
  __syncthreads();

  // ---- P10: LayerNorm over D ----
  float ln[DMOD];
  if (act) {
    float s2v[DMOD];
    #pragma unroll
    for (int d = 0; d < DMOD; ++d) s2v[d] = pool[half][d * LLEN + l];
    float m = 0.f;
    #pragma unroll
    for (int d = 0; d < DMOD; ++d) m += s2v[d];
    m *= (1.f / DMOD);
    float va = 0.f;
    #pragma unroll
    for (int d = 0; d < DMOD; ++d) { const float z = s2v[d] - m; va += z * z; }
    va *= (1.f / DMOD);
    const float inv = rsqrtf(va + LN_EPS);
    #pragma unroll
    for (int d = 0; d < DMOD; ++d) ln[d] = (s2v[d] - m) * inv * g_norm[d] + b_norm[d];
  } else {
    #pragma unroll
    for (int d = 0; d < DMOD; ++d) ln[d] = 0.f;
  }
  __syncthreads();

  // ---- P11: u = adj @ ln ----
  float u[DMOD];
  #pragma unroll
  for (int i = 0; i < DMOD; ++i) {
    const float4* ar = (const float4*)&adjLDS[i][0];
    const float4 c0 = ar[0], c1 = ar[1], c2 = ar[2];
    const float2 c3 = ((const float2*)ar)[6];
    u[i] = c0.x * ln[0] + c0.y * ln[1] + c0.z * ln[2] + c0.w * ln[3]
         + c1.x * ln[4] + c1.y * ln[5] + c1.z * ln[6] + c1.w * ln[7]
         + c2.x * ln[8] + c2.y * ln[9] + c2.z * ln[10] + c2.w * ln[11]
         + c3.x * ln[12] + c3.y * ln[13];
  }
  if (act) {
    float4* ur = (float4*)&pool[half][l * 16];
    ur[0] = make_float4(u[0], u[1], u[2], u[3]);
    ur[1] = make_float4(u[4], u[5], u[6], u[7]);
    ur[2] = make_float4(u[8], u[9], u[10], u[11]);
    ((float2*)ur)[6] = make_float2(u[12], u[13]);
  }
  __syncthreads();

  // ---- P12: dy + write f (stride 448, bf16) ----
  if (live) {
    float acc[DMOD];
    #pragma unroll
    for (int i = 0; i < DMOD; ++i) acc[i] = 0.f;
    #pragma unroll 5
    for (int lp = 0; lp < LLEN; ++lp) {
      const float wd = W_dy[lp * LLEN + l];
      const float4* ur = (const float4*)&pool[half][lp * 16];
      const float4 a0 = ur[0], a1 = ur[1], a2 = ur[2];
      const float2 a3 = ((const float2*)ur)[6];
      acc[0] += a0.x * wd;  acc[1] += a0.y * wd;  acc[2]  += a0.z * wd;  acc[3]  += a0.w * wd;
      acc[4] += a1.x * wd;  acc[5] += a1.y * wd;  acc[6]  += a1.z * wd;  acc[7]  += a1.w * wd;
      acc[8] += a2.x * wd;  acc[9] += a2.y * wd;  acc[10] += a2.z * wd;  acc[11] += a2.w * wd;
      acc[12] += a3.x * wd; acc[13] += a3.y * wd;
    }
    const float bd = b_dy[l];
    u16* fo = f_out + (size_t)b * K1P + l;
    #pragma unroll
    for (int i = 0; i < DMOD; ++i)
      fo[i * LLEN] = f2bf(fmaxf(acc[i] + bd, 0.f));
  }
}

// ========================= Weight prep (one-time-ish) =======================
// Slot-major bf16 fragment records, 16B each = W^T[row][k0..k0+7]:
//   rec index = (chunk*4 + slot)*NROWS + row, k0 = 8*(chunk*4+slot).
// Rows k>=420 zero-padded (W1/Wres). Wres/W2 stored as hi/lo bf16 split so
// their effective precision matches the previous fp32-weight path.
__global__ void prep_kernel(const float* __restrict__ W1,
                            const float* __restrict__ Wres,
                            const float* __restrict__ W2,
                            u16* __restrict__ w1s,
                            u16* __restrict__ wrh, u16* __restrict__ wrl,
                            u16* __restrict__ w2h, u16* __restrict__ w2l)
{
  const int idx = blockIdx.x * 256 + threadIdx.x;
  if (idx < NREC_W1) {
    const int n1 = idx & 255;
    const int cs = idx >> 8;
    const int k0 = cs * 8;
    union { u16 h[8]; uint4 q; } R;
    #pragma unroll
    for (int i = 0; i < 8; ++i) {
      const int k = k0 + i;
      const float w = (k < 420) ? W1[k * 256 + n1] : 0.f;
      R.h[i] = f2bf(w);
    }
    *((uint4*)(w1s + (size_t)idx * 8)) = R.q;
  } else if (idx < NREC_W1 + NREC_WR) {
    const int id = idx - NREC_W1;
    const int row = id & 63;
    const int cs = id >> 6;
    const int k0 = cs * 8;
    union { u16 h[8]; uint4 q; } Rh, Rl;
    #pragma unroll
    for (int i = 0; i < 8; ++i) {
      const int k = k0 + i;
      const float w = (k < 420) ? Wres[k * 64 + row] : 0.f;
      const u16 hh = f2bf(w);
      Rh.h[i] = hh;
      Rl.h[i] = f2bf(w - bflo((u32)hh));
    }
    *((uint4*)(wrh + (size_t)id * 8)) = Rh.q;
    *((uint4*)(wrl + (size_t)id * 8)) = Rl.q;
  } else if (idx < NREC_W1 + NREC_WR + NREC_W2) {
    const int id = idx - NREC_W1 - NREC_WR;
    const int row = id & 63;
    const int cs = id >> 6;
    const int k0 = cs * 8;
    union { u16 h[8]; uint4 q; } Rh, Rl;
    #pragma unroll
    for (int i = 0; i < 8; ++i) {
      const float w = W2[(k0 + i) * 64 + row];
      const u16 hh = f2bf(w);
      Rh.h[i] = hh;
      Rl.h[i] = f2bf(w - bflo((u32)hh));
    }
    *((uint4*)(w2h + (size_t)id * 8)) = Rh.q;
    *((uint4*)(w2l + (size_t)id * 8)) = Rl.q;
  }
}

// ============================ MFMA MLP head =================================
// Swapped orientation: D = W^T @ f^T via mfma_f32_16x16x32_bf16. One wave owns
// 16 samples; col(lane&15) = sample, rows = output features. The f-fragments
// (lane holds f[sample][8 consecutive k]) serve as the B operand of BOTH the
// W1 GEMM and the Wres GEMM. h->bf16 repack for h@W2 is in-register via
// 4x f2bf-pack + 8x ds_bpermute per K-chunk. No LDS, no barriers.
__global__ __launch_bounds__(256, 2) void head_mfma(
    const u16* __restrict__ f, const u16* __restrict__ w1s,
    const u16* __restrict__ wrh, const u16* __restrict__ wrl,
    const u16* __restrict__ w2h, const u16* __restrict__ w2l,
    const float* __restrict__ b1, const float* __restrict__ b2,
    const float* __restrict__ bres, const float* __restrict__ g_ln,
    const float* __restrict__ b_ln, const float* __restrict__ W3,
    const float* __restrict__ b3, float* __restrict__ out, int Btot)
{
  const int lane = threadIdx.x & 63;
  const int wv   = threadIdx.x >> 6;
  const int g    = lane >> 4;       // k-slot / row-quadrant
  const int m    = lane & 15;       // sample within wave
  const int samp = blockIdx.x * 64 + wv * 16 + m;
  const int srow = (samp < Btot) ? samp : (Btot - 1);

  // f fragments: fr[c] = f[samp][32c + 8g .. +7]  (56 VGPRs, live whole kernel)
  s16x8 fr[14];
  const u16* fp = f + (size_t)srow * K1P + g * 8;
  #pragma unroll
  for (int c = 0; c < 14; ++c)
    fr[c] = *((const s16x8*)(fp + 32 * c));

  const f32x4 zero4 = {0.f, 0.f, 0.f, 0.f};

  // ---- residual: r = f @ Wres (hi + lo) ----
  f32x4 ac3[4] = {zero4, zero4, zero4, zero4};
  #pragma unroll
  for (int c = 0; c < 14; ++c) {
    const int bo = (c * 4 + g) * 512 + m * 8;
    #pragma unroll
    for (int nt = 0; nt < 4; ++nt) {
      const s16x8 ah = *((const s16x8*)(wrh + bo + nt * 128));
      ac3[nt] = __builtin_amdgcn_mfma_f32_16x16x32_bf16(ah, fr[c], ac3[nt], 0, 0, 0);
    }
    #pragma unroll
    for (int nt = 0; nt < 4; ++nt) {
      const s16x8 al = *((const s16x8*)(wrl + bo + nt * 128));
      ac3[nt] = __builtin_amdgcn_mfma_f32_16x16x32_bf16(al, fr[c], ac3[nt], 0, 0, 0);
    }
  }

  // ---- h = relu(f@W1 + b1) ; out2 = h @ W2 (hi + lo) ----
  f32x4 ac2[4] = {zero4, zero4, zero4, zero4};
  const int ap0 = ((g & 1) << 7) + (m << 2);  // bpermute byte addr, quadrant 2*(g&1)
  const int ap1 = ap0 + 64;                   // quadrant 2*(g&1)+1
  #pragma unroll 1
  for (int j = 0; j < 8; ++j) {
    f32x4 ha = zero4, hb = zero4;             // h-feature tiles 2j, 2j+1
    #pragma unroll
    for (int c = 0; c < 14; ++c) {
      const int bo = (c * 4 + g) * 2048 + m * 8;
      const s16x8 wa = *((const s16x8*)(w1s + bo + (2 * j) * 128));
      const s16x8 wb = *((const s16x8*)(w1s + bo + (2 * j + 1) * 128));
      ha = __builtin_amdgcn_mfma_f32_16x16x32_bf16(wa, fr[c], ha, 0, 0, 0);
      hb = __builtin_amdgcn_mfma_f32_16x16x32_bf16(wb, fr[c], hb, 0, 0, 0);
    }
    // lane holds h[feature 32j + {0,16} + 4g + r][sample m]
    const int f0 = 32 * j + 4 * g;
    const float H00 = fmaxf(ha[0] + b1[f0 + 0], 0.f);
    const float H01 = fmaxf(ha[1] + b1[f0 + 1], 0.f);
    const float H02 = fmaxf(ha[2] + b1[f0 + 2], 0.f);
    const float H03 = fmaxf(ha[3] + b1[f0 + 3], 0.f);
    const float H10 = fmaxf(hb[0] + b1[f0 + 16], 0.f);
    const float H11 = fmaxf(hb[1] + b1[f0 + 17], 0.f);
    const float H12 = fmaxf(hb[2] + b1[f0 + 18], 0.f);
    const float H13 = fmaxf(hb[3] + b1[f0 + 19], 0.f);
    // PK[a][b] = pack(H[b][2a], H[b][2a+1]); dest frag p pulls PK[p&1][g>>1]
    // from lane 16*(2*(g&1) + (p>>1)) + m.
    const u32 PK00 = pk2(H00, H01), PK01 = pk2(H10, H11);
    const u32 PK10 = pk2(H02, H03), PK11 = pk2(H12, H13);
    union { u32 u[4]; s16x8 v; } bb;
    {
      const u32 r0 = (u32)__builtin_amdgcn_ds_bpermute(ap0, (int)PK00);
      const u32 r1 = (u32)__builtin_amdgcn_ds_bpermute(ap0, (int)PK01);
      bb.u[0] = (g & 2) ? r1 : r0;
    }
    {
      const u32 r0 = (u32)__builtin_amdgcn_ds_bpermute(ap0, (int)PK10);
      const u32 r1 = (u32)__builtin_amdgcn_ds_bpermute(ap0, (int)PK11);
      bb.u[1] = (g & 2) ? r1 : r0;
    }
    {
      const u32 r0 = (u32)__builtin_amdgcn_ds_bpermute(ap1, (int)PK00);
      const u32 r1 = (u32)__builtin_amdgcn_ds_bpermute(ap1, (int)PK01);
      bb.u[2] = (g & 2) ? r1 : r0;
    }
    {
      const u32 r0 = (u32)__builtin_amdgcn_ds_bpermute(ap1, (int)PK10);
      const u32 r1 = (u32)__builtin_amdgcn_ds_bpermute(ap1, (int)PK11);
      bb.u[3] = (g & 2) ? r1 : r0;
    }
    const int bo2 = (j * 4 + g) * 512 + m * 8;
    #pragma unroll
    for (int nt = 0; nt < 4; ++nt) {
      const s16x8 a2h = *((const s16x8*)(w2h + bo2 + nt * 128));
      ac2[nt] = __builtin_amdgcn_mfma_f32_16x16x32_bf16(a2h, bb.v, ac2[nt], 0, 0, 0);
    }
    #pragma unroll
    for (int nt = 0; nt < 4; ++nt) {
      const s16x8 a2l = *((const s16x8*)(w2l + bo2 + nt * 128));
      ac2[nt] = __builtin_amdgcn_mfma_f32_16x16x32_bf16(a2l, bb.v, ac2[nt], 0, 0, 0);
    }
  }

  // ---- LayerNorm over 64 features + dot W3 ----
  // lane holds output features fe = 16*nt + 4*g + r of sample m; the 4 lanes
  // {g=0..3, same m} jointly hold all 64 -> reduce via shfl_xor 16/32.
  float vals[4][4];
  float s1 = 0.f, sq = 0.f;
  #pragma unroll
  for (int nt = 0; nt < 4; ++nt) {
    #pragma unroll
    for (int r = 0; r < 4; ++r) {
      const int fe = 16 * nt + 4 * g + r;
      const float val = ac2[nt][r] + ac3[nt][r] + b2[fe] + bres[fe];
      vals[nt][r] = val; s1 += val; sq += val * val;
    }
  }
  s1 += __shfl_xor(s1, 16); s1 += __shfl_xor(s1, 32);
  sq += __shfl_xor(sq, 16); sq += __shfl_xor(sq, 32);
  const float mean = s1 * (1.f / 64.f);
  const float var  = sq * (1.f / 64.f) - mean * mean;
  const float inv  = rsqrtf(var + LN_EPS);
  float pr = 0.f;
  #pragma unroll
  for (int nt = 0; nt < 4; ++nt) {
    #pragma unroll
    for (int r = 0; r < 4; ++r) {
      const int fe = 16 * nt + 4 * g + r;
      const float n = (vals[nt][r] - mean) * inv * g_ln[fe] + b_ln[fe];
      pr += n * W3[fe];
    }
  }
  pr += __shfl_xor(pr, 16); pr += __shfl_xor(pr, 32);
  if (g == 0 && samp < Btot) out[samp] = pr + b3[0];
}

extern "C" void kernel_launch(void* const* d_in, const int* in_sizes, int n_in,
                              void* d_out, int out_size, void* d_ws, size_t ws_size,
                              hipStream_t stream) {
  const float* x        = (const float*)d_in[0];
  const float* W_emb    = (const float*)d_in[1];
  const float* b_emb    = (const float*)d_in[2];
  const float* Wq       = (const float*)d_in[3];
  const float* bq       = (const float*)d_in[4];
  const float* Wk       = (const float*)d_in[5];
  const float* bk       = (const float*)d_in[6];
  const float* Wv       = (const float*)d_in[7];
  const float* bv       = (const float*)d_in[8];
  const float* Wo       = (const float*)d_in[9];
  const float* bo       = (const float*)d_in[10];
  const float* W_ff1    = (const float*)d_in[11];
  const float* W_ff2    = (const float*)d_in[12];
  const float* g_norm   = (const float*)d_in[13];
  const float* b_norm   = (const float*)d_in[14];
  const float* W_dy     = (const float*)d_in[15];
  const float* b_dy     = (const float*)d_in[16];
  const float* channels = (const float*)d_in[17];
  const float* W1       = (const float*)d_in[18];
  const float* b1       = (const float*)d_in[19];
  const float* W2       = (const float*)d_in[20];
  const float* b2       = (const float*)d_in[21];
  const float* Wres     = (const float*)d_in[22];
  const float* bres     = (const float*)d_in[23];
  const float* g_ln     = (const float*)d_in[24];
  const float* b_ln     = (const float*)d_in[25];
  const float* W3       = (const float*)d_in[26];
  const float* b3       = (const float*)d_in[27];

  const int B = in_sizes[0] / (LLEN * DMOD);

  // workspace layout (u16 units, all 16B aligned):
  //   fbuf: B*448 | W1s: 14336*8 | WresHi/Lo: 3584*8 each | W2Hi/Lo: 2048*8 each
  u16* fbuf = (u16*)d_ws;
  u16* w1s  = fbuf + (size_t)B * K1P;
  u16* wrh  = w1s + (size_t)NREC_W1 * 8;
  u16* wrl  = wrh + (size_t)NREC_WR * 8;
  u16* w2h  = wrl + (size_t)NREC_WR * 8;
  u16* w2l  = w2h + (size_t)NREC_W2 * 8;

  prep_kernel<<<78, 256, 0, stream>>>(W1, Wres, W2, w1s, wrh, wrl, w2h, w2l);

  const int nb_fe = (B + 1) / 2;
  fe_kernel<<<nb_fe, 64, 0, stream>>>(x, W_emb, b_emb, Wq, bq, Wk, bk, Wv, bv, Wo, bo,
                                      W_ff1, W_ff2, g_norm, b_norm, W_dy, b_dy, channels,
                                      fbuf, B);

  const int nb_h = (B + 63) / 64;
  head_mfma<<<nb_h, 256, 0, stream>>>(fbuf, w1s, wrh, wrl, w2h, w2l,
                                      b1, b2, bres, g_ln, b_ln, W3, b3,
                                      (float*)d_out, B);
}